// Round 8
// baseline (1392.718 us; speedup 1.0000x reference)
//
#include <hip/hip_runtime.h>
#include <hip/hip_bf16.h>

#define NN 80000
#define EE 320000
#define ET 400000   // EE + NN self loops
#define BB 3200
#define LL 5
#define NBLK 313     // ceil(NN/256)
#define MLPB 1250    // NN/64 row-blocks for fused MLP

typedef __attribute__((ext_vector_type(8))) short bf16x8;
typedef __attribute__((ext_vector_type(8))) unsigned short u16x8;
typedef __attribute__((ext_vector_type(4))) float f32x4;

__device__ __forceinline__ float bf2f(unsigned short u) {
    unsigned int v = ((unsigned int)u) << 16;
    return __builtin_bit_cast(float, v);
}
__device__ __forceinline__ unsigned short f2bf(float f) {
    return __builtin_bit_cast(unsigned short, __float2bfloat16(f));
}

// ---------------- preprocessing ----------------

__global__ void k_deg(const int* ei, int* deg) {
    int e = blockIdx.x * 256 + threadIdx.x;
    if (e >= ET) return;
    int d = (e < EE) ? ei[EE + e] : (e - EE);
    atomicAdd(&deg[d], 1);
}

__global__ void k_scan1(const int* deg, int* blksum) {
    __shared__ int sh[256];
    int t = threadIdx.x, b = blockIdx.x;
    int i = b * 256 + t;
    int v = (i < NN) ? deg[i] : 0;
    sh[t] = v; __syncthreads();
    for (int off = 128; off > 0; off >>= 1) {
        if (t < off) sh[t] += sh[t + off];
        __syncthreads();
    }
    if (t == 0) blksum[b] = sh[0];
}

__global__ __launch_bounds__(512) void k_scan2(const int* blksum, int* blkoff) {
    __shared__ int sh[512];
    int t = threadIdx.x;
    int v = (t < NBLK) ? blksum[t] : 0;
    sh[t] = v; __syncthreads();
    for (int off = 1; off < 512; off <<= 1) {
        int x = (t >= off) ? sh[t - off] : 0;
        __syncthreads();
        sh[t] += x;
        __syncthreads();
    }
    if (t < NBLK) blkoff[t] = sh[t] - v;   // exclusive
}

__global__ void k_scan3(const int* deg, const int* blkoff, int* row_start, int* cursor) {
    __shared__ int sh[256];
    int t = threadIdx.x, b = blockIdx.x;
    int i = b * 256 + t;
    int v = (i < NN) ? deg[i] : 0;
    sh[t] = v; __syncthreads();
    for (int off = 1; off < 256; off <<= 1) {
        int x = (t >= off) ? sh[t - off] : 0;
        __syncthreads();
        sh[t] += x;
        __syncthreads();
    }
    int exc = sh[t] - v + blkoff[b];
    if (i < NN) { row_start[i] = exc; cursor[i] = exc; }
    if (i == NN - 1) row_start[NN] = exc + v;
}

__global__ void k_fill(const int* ei, const int* ea, int* cursor, int* eid, int* combo) {
    int e = blockIdx.x * 256 + threadIdx.x;
    if (e >= ET) return;
    int d = (e < EE) ? ei[EE + e] : (e - EE);
    int p = atomicAdd(&cursor[d], 1);
    eid[p] = e;
    int c;
    if (e < EE) c = ea[e * 3 + 0] * 12 + ea[e * 3 + 1] * 2 + ea[e * 3 + 2];
    else        c = 22 * 12;   // self loop attr [22,0,0]
    combo[e] = c;
}

// deterministic edge order within each node bucket (atomics fill in random order)
__global__ void k_sortbkt(const int* row_start, int* eid) {
    int v = blockIdx.x * 256 + threadIdx.x;
    if (v >= NN) return;
    int s0 = row_start[v], s1 = row_start[v + 1];
    for (int i = s0 + 1; i < s1; i++) {
        int key = eid[i];
        int j = i - 1;
        while (j >= s0 && eid[j] > key) { eid[j + 1] = eid[j]; j--; }
        eid[j + 1] = key;
    }
}

// flatten eid indirection: csrc[p]=source node, ccomb[p]=edge combo, in CSR order
__global__ void k_remap(const int* eid, const int* combo, const int* ei_src,
                        int* csrc, int* ccomb) {
    int p = blockIdx.x * 256 + threadIdx.x;
    if (p >= ET) return;
    int e = eid[p];
    csrc[p]  = (e < EE) ? ei_src[e] : (e - EE);
    ccomb[p] = combo[e];
}

__global__ void k_ecomb(const float* e1, const float* e2, const float* e3, float* ec) {
    int l = blockIdx.x / 300, c = blockIdx.x % 300, d = threadIdx.x;
    int a0 = c / 12, a1 = (c / 2) % 6, a2 = c & 1;
    ec[(size_t)(l * 300 + c) * 256 + d] =
        e1[(size_t)(l * 25 + a0) * 256 + d] +
        e2[(size_t)(l * 6 + a1) * 256 + d] +
        e3[(size_t)(l * 2 + a2) * 256 + d];
}

// W1: [L][256][512] -> hi/lo bf16 pair in [L][512][256] layout (transposed)
__global__ void k_w1t(const float* W, __hip_bfloat16* Whi, __hip_bfloat16* Wlo) {
    int i = blockIdx.x * 256 + threadIdx.x;
    if (i >= LL * 512 * 256) return;
    int l = i / (512 * 256); int r = i % (512 * 256); int n = r / 256; int k = r % 256;
    float w = W[(size_t)(l * 256 + k) * 512 + n];
    unsigned short hi = f2bf(w);
    Whi[i] = __float2bfloat16(w);
    Wlo[i] = __float2bfloat16(w - bf2f(hi));
}
// W2: [L][512][256] -> hi/lo bf16 pair in [L][256][512] layout (transposed)
__global__ void k_w2t(const float* W, __hip_bfloat16* Whi, __hip_bfloat16* Wlo) {
    int i = blockIdx.x * 256 + threadIdx.x;
    if (i >= LL * 256 * 512) return;
    int l = i / (256 * 512); int r = i % (256 * 512); int n = r / 512; int k = r % 512;
    float w = W[(size_t)(l * 512 + k) * 256 + n];
    unsigned short hi = f2bf(w);
    Whi[i] = __float2bfloat16(w);
    Wlo[i] = __float2bfloat16(w - bf2f(hi));
}

__global__ void k_nodeemb(const int* x, const float* emb, __hip_bfloat16* h) {
    const int offs[9] = {0, 121, 129, 141, 156, 166, 175, 182, 185};
    int i = blockIdx.x; int d = threadIdx.x;
    float acc = 0.f;
#pragma unroll
    for (int c = 0; c < 9; c++) {
        int idx = x[i * 9 + c] + offs[c];
        acc += emb[(size_t)idx * 256 + d];
    }
    h[(size_t)i * 256 + d] = __float2bfloat16(acc);
}

// ---------------- per-layer ----------------

// 2 nodes per wave: lanes 0-31 -> node A, 32-63 -> node B; 8 cols (16B) per lane.
__global__ __launch_bounds__(256) void k_aggr(const __hip_bfloat16* h, const float* ecomb_l,
        const int* row_start, const int* csrc, const int* ccomb,
        __hip_bfloat16* aggrB) {
    int wid = threadIdx.x >> 6;
    int lane = threadIdx.x & 63;
    int v = blockIdx.x * 8 + wid * 2 + (lane >> 5);   // NN=80000 = 10000*8, always valid
    int sl = lane & 31;
    int s0 = row_start[v], s1 = row_start[v + 1];
    const unsigned short* hp = (const unsigned short*)h;
    float acc[8] = {0.f, 0.f, 0.f, 0.f, 0.f, 0.f, 0.f, 0.f};
    for (int p = s0; p < s1; p++) {
        int s = csrc[p];
        int c = ccomb[p];
        u16x8 hv = *(const u16x8*)(hp + (size_t)s * 256 + sl * 8);
        f32x4 e0 = *(const f32x4*)(ecomb_l + (size_t)c * 256 + sl * 8);
        f32x4 e1 = *(const f32x4*)(ecomb_l + (size_t)c * 256 + sl * 8 + 4);
        acc[0] += bf2f(hv[0]) + e0.x;
        acc[1] += bf2f(hv[1]) + e0.y;
        acc[2] += bf2f(hv[2]) + e0.z;
        acc[3] += bf2f(hv[3]) + e0.w;
        acc[4] += bf2f(hv[4]) + e1.x;
        acc[5] += bf2f(hv[5]) + e1.y;
        acc[6] += bf2f(hv[6]) + e1.z;
        acc[7] += bf2f(hv[7]) + e1.w;
    }
    u16x8 o;
#pragma unroll
    for (int j = 0; j < 8; j++) o[j] = f2bf(acc[j]);
    *(u16x8*)((unsigned short*)aggrB + (size_t)v * 256 + sl * 8) = o;
}

// Fused MLP with dual-bf16 (hi+lo) weights:
//   h2 = (relu(A @ W1 + b1)) @ W2 + b2, + BN column partials.
// M=64 rows/block, 8 waves (512 thr), act[64][512] bf16 lives only in LDS (64KB,
// row-XOR swizzled: col8blk ^= row&7, same XOR on write and read).
// GEMM1: wave owns 64 cols of 512; GEMM2: wave owns 32 cols of 256.
// LAST: store h2 only for supernode rows (row%25==24).
template<bool LAST>
__global__ __launch_bounds__(512) void k_mlp(const __hip_bfloat16* aggrB,
        const __hip_bfloat16* W1hi, const __hip_bfloat16* W1lo, const float* b1v,
        const __hip_bfloat16* W2hi, const __hip_bfloat16* W2lo, const float* b2v,
        float* h2, float* psum, float* psq) {
    __shared__ short sAct[64 * 512];
    int tid = threadIdx.x;
    int wave = tid >> 6, lane = tid & 63;
    int lr = lane & 15, lk = lane >> 4;
    int mBase = blockIdx.x * 64;

    // ---- GEMM1: act[64][512] ----
    const short* Ap  = (const short*)aggrB + (size_t)mBase * 256;
    const short* B1h = (const short*)W1hi + (size_t)(wave * 64) * 256;
    const short* B1l = (const short*)W1lo + (size_t)(wave * 64) * 256;
    f32x4 acc1[4][4] = {};
#pragma unroll 1
    for (int t = 0; t < 8; t++) {
        int k0 = t * 32;
        bf16x8 a[4], bh[4], bl[4];
#pragma unroll
        for (int m = 0; m < 4; m++)
            a[m] = *(const bf16x8*)(Ap + (size_t)(m * 16 + lr) * 256 + k0 + lk * 8);
#pragma unroll
        for (int n = 0; n < 4; n++) {
            bh[n] = *(const bf16x8*)(B1h + (size_t)(n * 16 + lr) * 256 + k0 + lk * 8);
            bl[n] = *(const bf16x8*)(B1l + (size_t)(n * 16 + lr) * 256 + k0 + lk * 8);
        }
#pragma unroll
        for (int m = 0; m < 4; m++)
#pragma unroll
            for (int n = 0; n < 4; n++) {
                acc1[m][n] = __builtin_amdgcn_mfma_f32_16x16x32_bf16(a[m], bh[n], acc1[m][n], 0, 0, 0);
                acc1[m][n] = __builtin_amdgcn_mfma_f32_16x16x32_bf16(a[m], bl[n], acc1[m][n], 0, 0, 0);
            }
    }
#pragma unroll
    for (int m = 0; m < 4; m++)
#pragma unroll
        for (int n = 0; n < 4; n++) {
            int col = wave * 64 + n * 16 + lr;
            float bi = b1v[col];
            int cb = col >> 3, ci = col & 7;
#pragma unroll
            for (int j = 0; j < 4; j++) {
                int row = m * 16 + lk * 4 + j;
                float v = fmaxf(acc1[m][n][j] + bi, 0.f);
                sAct[row * 512 + ((cb ^ (row & 7)) << 3) + ci] = (short)f2bf(v);
            }
        }
    __syncthreads();

    // ---- GEMM2: h2[64][256] ----
    const short* B2h = (const short*)W2hi + (size_t)(wave * 32) * 512;
    const short* B2l = (const short*)W2lo + (size_t)(wave * 32) * 512;
    f32x4 acc2[4][2] = {};
#pragma unroll 1
    for (int t = 0; t < 16; t++) {
        int kb = t * 4 + lk;   // this lane's col8-block: cols t*32 + lk*8
        bf16x8 a2[4], b2h[2], b2l[2];
#pragma unroll
        for (int m = 0; m < 4; m++) {
            int row = m * 16 + lr;
            a2[m] = *(const bf16x8*)(&sAct[row * 512 + ((kb ^ (row & 7)) << 3)]);
        }
#pragma unroll
        for (int n = 0; n < 2; n++) {
            b2h[n] = *(const bf16x8*)(B2h + (size_t)(n * 16 + lr) * 512 + t * 32 + lk * 8);
            b2l[n] = *(const bf16x8*)(B2l + (size_t)(n * 16 + lr) * 512 + t * 32 + lk * 8);
        }
#pragma unroll
        for (int m = 0; m < 4; m++)
#pragma unroll
            for (int n = 0; n < 2; n++) {
                acc2[m][n] = __builtin_amdgcn_mfma_f32_16x16x32_bf16(a2[m], b2h[n], acc2[m][n], 0, 0, 0);
                acc2[m][n] = __builtin_amdgcn_mfma_f32_16x16x32_bf16(a2[m], b2l[n], acc2[m][n], 0, 0, 0);
            }
    }

    float colS[2] = {0.f, 0.f}, colQ[2] = {0.f, 0.f};
#pragma unroll
    for (int m = 0; m < 4; m++)
#pragma unroll
        for (int n = 0; n < 2; n++) {
            int col = wave * 32 + n * 16 + lr;
            float bi = b2v[col];
#pragma unroll
            for (int j = 0; j < 4; j++) {
                int row = mBase + m * 16 + lk * 4 + j;
                float v = acc2[m][n][j] + bi;
                colS[n] += v; colQ[n] += v * v;
                if (!LAST || (row % 25 == 24))
                    h2[(size_t)row * 256 + col] = v;
            }
        }
#pragma unroll
    for (int n = 0; n < 2; n++) {
        colS[n] += __shfl_xor(colS[n], 16);
        colQ[n] += __shfl_xor(colQ[n], 16);
        colS[n] += __shfl_xor(colS[n], 32);
        colQ[n] += __shfl_xor(colQ[n], 32);
    }
    if (lk == 0) {
#pragma unroll
        for (int n = 0; n < 2; n++) {
            int col = wave * 32 + n * 16 + lr;
            psum[(size_t)col * MLPB + blockIdx.x] = colS[n];
            psq [(size_t)col * MLPB + blockIdx.x] = colQ[n];
        }
    }
}

// one block per column: reduce MLPB row-block partials -> scale/shift
__global__ __launch_bounds__(256) void k_bn2(const float* psum, const float* psq,
                                             const float* g, const float* bta, float* stat) {
    __shared__ float s1[256], s2[256];
    int d = blockIdx.x; int t = threadIdx.x;
    float a = 0.f, b = 0.f;
    for (int rb = t; rb < MLPB; rb += 256) {
        a += psum[(size_t)d * MLPB + rb];
        b += psq [(size_t)d * MLPB + rb];
    }
    s1[t] = a; s2[t] = b; __syncthreads();
    for (int off = 128; off > 0; off >>= 1) {
        if (t < off) { s1[t] += s1[t + off]; s2[t] += s2[t + off]; }
        __syncthreads();
    }
    if (t == 0) {
        float mean = s1[0] / NN;
        float var = s2[0] / NN - mean * mean;
        float sc = rsqrtf(var + 1e-5f) * g[d];
        stat[d] = sc;
        stat[256 + d] = bta[d] - mean * sc;
    }
}

// vectorized: 4 f32 in, 4 bf16 out per thread; grid covers NN*256/4 threads
__global__ void k_bnapply(const float* h2, const float* stat, __hip_bfloat16* h, int relu) {
    int i = (blockIdx.x * 256 + threadIdx.x) * 4;   // over NN*256
    int d = i & 255;
    f32x4 v = *(const f32x4*)(h2 + i);
    f32x4 sc = *(const f32x4*)(stat + d);
    f32x4 sh = *(const f32x4*)(stat + 256 + d);
    float r0 = v.x * sc.x + sh.x;
    float r1 = v.y * sc.y + sh.y;
    float r2 = v.z * sc.z + sh.z;
    float r3 = v.w * sc.w + sh.w;
    if (relu) {
        r0 = fmaxf(r0, 0.f); r1 = fmaxf(r1, 0.f);
        r2 = fmaxf(r2, 0.f); r3 = fmaxf(r3, 0.f);
    }
    ushort4 o;
    o.x = f2bf(r0); o.y = f2bf(r1); o.z = f2bf(r2); o.w = f2bf(r3);
    *(ushort4*)((unsigned short*)h + i) = o;
}

// ---------------- head ----------------
// reads last-layer h2 (f32) + bnstat directly: BN applied to only the 3200 super-nodes
__global__ __launch_bounds__(128) void k_head(const float* h2, const float* stat,
        const float* HW1, const float* Hb1, const float* HW2, const float* Hb2,
        const float* HW3, const float* Hb3, float* out) {
    __shared__ float row[256], z1[128], z2[128];
    int g = blockIdx.x; int t = threadIdx.x;
    size_t node = (size_t)g * 25 + 24;
    row[t]       = h2[node * 256 + t] * stat[t] + stat[256 + t];
    row[t + 128] = h2[node * 256 + t + 128] * stat[t + 128] + stat[256 + t + 128];
    __syncthreads();
    float acc = Hb1[t];
    for (int k = 0; k < 256; k++) acc += row[k] * HW1[k * 128 + t];
    z1[t] = acc > 0.f ? acc : expm1f(acc);
    __syncthreads();
    acc = Hb2[t];
    for (int k = 0; k < 128; k++) acc += z1[k] * HW2[k * 128 + t];
    z2[t] = acc > 0.f ? acc : expm1f(acc);
    __syncthreads();
    if (t < 2) {
        acc = Hb3[t];
        for (int k = 0; k < 128; k++) acc += z2[k] * HW3[k * 2 + t];
        out[g * 2 + t] = acc;
    }
}

// ---------------- launch ----------------

extern "C" void kernel_launch(void* const* d_in, const int* in_sizes, int n_in,
                              void* d_out, int out_size, void* d_ws, size_t ws_size,
                              hipStream_t stream) {
    const int* x          = (const int*)d_in[0];
    const int* edge_index = (const int*)d_in[1];
    const int* edge_attr  = (const int*)d_in[2];
    const float* node_emb = (const float*)d_in[4];
    const float* ee1 = (const float*)d_in[5];
    const float* ee2 = (const float*)d_in[6];
    const float* ee3 = (const float*)d_in[7];
    const float* W1  = (const float*)d_in[8];
    const float* b1  = (const float*)d_in[9];
    const float* W2  = (const float*)d_in[10];
    const float* b2  = (const float*)d_in[11];
    const float* bng = (const float*)d_in[12];
    const float* bnb = (const float*)d_in[13];
    const float* HW1 = (const float*)d_in[14];
    const float* Hb1 = (const float*)d_in[15];
    const float* HW2 = (const float*)d_in[16];
    const float* Hb2 = (const float*)d_in[17];
    const float* HW3 = (const float*)d_in[18];
    const float* Hb3 = (const float*)d_in[19];
    float* out = (float*)d_out;

    char* ws = (char*)d_ws;
    size_t off = 0;
    auto alloc = [&](size_t bytes) -> char* {
        off = (off + 255) & ~(size_t)255;
        char* p = ws + off;
        off += bytes;
        return p;
    };
    int* deg       = (int*)alloc((size_t)NN * 4);
    int* cursor    = (int*)alloc((size_t)NN * 4);
    int* row_start = (int*)alloc((size_t)(NN + 1) * 4);
    int* blksum    = (int*)alloc((size_t)(NBLK + 1) * 4);
    int* blkoff    = (int*)alloc((size_t)(NBLK + 1) * 4);
    int* eid       = (int*)alloc((size_t)ET * 4);
    int* combo     = (int*)alloc((size_t)ET * 4);
    int* csrc      = (int*)alloc((size_t)ET * 4);
    int* ccomb     = (int*)alloc((size_t)ET * 4);
    float* ecomb   = (float*)alloc((size_t)LL * 300 * 256 * 4);
    __hip_bfloat16* W1hi = (__hip_bfloat16*)alloc((size_t)LL * 512 * 256 * 2);
    __hip_bfloat16* W1lo = (__hip_bfloat16*)alloc((size_t)LL * 512 * 256 * 2);
    __hip_bfloat16* W2hi = (__hip_bfloat16*)alloc((size_t)LL * 256 * 512 * 2);
    __hip_bfloat16* W2lo = (__hip_bfloat16*)alloc((size_t)LL * 256 * 512 * 2);
    __hip_bfloat16* h    = (__hip_bfloat16*)alloc((size_t)NN * 256 * 2);
    __hip_bfloat16* aggrB = (__hip_bfloat16*)alloc((size_t)NN * 256 * 2);
    float* h2     = (float*)alloc((size_t)NN * 256 * 4);
    float* psum   = (float*)alloc((size_t)256 * MLPB * 4);
    float* psq    = (float*)alloc((size_t)256 * MLPB * 4);
    float* bnstat = (float*)alloc((size_t)512 * 4);

    hipMemsetAsync(deg, 0, (size_t)NN * 4, stream);
    k_deg<<<(ET + 255) / 256, 256, 0, stream>>>(edge_index, deg);
    k_scan1<<<NBLK, 256, 0, stream>>>(deg, blksum);
    k_scan2<<<1, 512, 0, stream>>>(blksum, blkoff);
    k_scan3<<<NBLK, 256, 0, stream>>>(deg, blkoff, row_start, cursor);
    k_fill<<<(ET + 255) / 256, 256, 0, stream>>>(edge_index, edge_attr, cursor, eid, combo);
    k_sortbkt<<<(NN + 255) / 256, 256, 0, stream>>>(row_start, eid);
    k_remap<<<(ET + 255) / 256, 256, 0, stream>>>(eid, combo, edge_index, csrc, ccomb);
    k_ecomb<<<LL * 300, 256, 0, stream>>>(ee1, ee2, ee3, ecomb);
    k_w1t<<<(LL * 512 * 256 + 255) / 256, 256, 0, stream>>>(W1, W1hi, W1lo);
    k_w2t<<<(LL * 256 * 512 + 255) / 256, 256, 0, stream>>>(W2, W2hi, W2lo);
    k_nodeemb<<<NN, 256, 0, stream>>>(x, node_emb, h);

    for (int l = 0; l < LL; l++) {
        k_aggr<<<NN / 8, 256, 0, stream>>>(h, ecomb + (size_t)l * 300 * 256, row_start,
                                           csrc, ccomb, aggrB);
        if (l < LL - 1) {
            k_mlp<false><<<MLPB, 512, 0, stream>>>(aggrB,
                W1hi + (size_t)l * 512 * 256, W1lo + (size_t)l * 512 * 256, b1 + l * 512,
                W2hi + (size_t)l * 256 * 512, W2lo + (size_t)l * 256 * 512, b2 + l * 256,
                h2, psum, psq);
        } else {
            k_mlp<true><<<MLPB, 512, 0, stream>>>(aggrB,
                W1hi + (size_t)l * 512 * 256, W1lo + (size_t)l * 512 * 256, b1 + l * 512,
                W2hi + (size_t)l * 256 * 512, W2lo + (size_t)l * 256 * 512, b2 + l * 256,
                h2, psum, psq);
        }
        k_bn2<<<256, 256, 0, stream>>>(psum, psq, bng + l * 256, bnb + l * 256, bnstat);
        if (l < LL - 1)
            k_bnapply<<<NN * 256 / (256 * 4), 256, 0, stream>>>(h2, bnstat, h, 1);
    }

    k_head<<<BB, 128, 0, stream>>>(h2, bnstat, HW1, Hb1, HW2, Hb2, HW3, Hb3, out);
}